// Round 13
// baseline (190.919 us; speedup 1.0000x reference)
//
#include <hip/hip_runtime.h>
#include <hip/hip_bf16.h>
#include <cstdint>
#include <cstddef>

#define T_TOK 8192
#define MDIM  4096
#define NEXP  64
#define CAP   128
#define TEC   ((size_t)T_TOK * NEXP * CAP)        // 67,108,864
#define OUTN  ((size_t)(1 + 2 * TEC))             // 134,217,729 floats

typedef __attribute__((ext_vector_type(8))) short bf16x8;   // 8 bf16 = 4 VGPR
typedef __attribute__((ext_vector_type(4))) float f32x4;    // MFMA acc

// split f32 -> hi bf16 + lo bf16 (residual), |err| ~ 2^-18 relative
__device__ __forceinline__ void split8(const float* f, bf16x8& h, bf16x8& l) {
#pragma unroll
  for (int j = 0; j < 8; ++j) {
    const __hip_bfloat16 hb = __float2bfloat16(f[j]);
    const float r = f[j] - __bfloat162float(hb);
    h[j] = __builtin_bit_cast(short, hb);
    l[j] = __builtin_bit_cast(short, __float2bfloat16(r));
  }
}

// async global->LDS, 16 bytes per lane (linear LDS dest: wavebase + lane*16)
__device__ __forceinline__ void gll16(const void* g, void* l) {
  __builtin_amdgcn_global_load_lds(
      (const __attribute__((address_space(1))) void*)g,
      (__attribute__((address_space(3))) void*)l, 16, 0, 0);
}

// counted wait: keep <=N vmem ops in flight past this point
template <int N>
__device__ __forceinline__ void vwait() {
  if constexpr (N == 0)       asm volatile("s_waitcnt vmcnt(0) lgkmcnt(0)" ::: "memory");
  else if constexpr (N == 10) asm volatile("s_waitcnt vmcnt(10) lgkmcnt(0)" ::: "memory");
}
__device__ __forceinline__ void barrier_now() {
  __builtin_amdgcn_s_barrier();
  asm volatile("" ::: "memory");
}

// ---------------------------------------------------------------------------
// One-time: wg (f32, [E][D]) -> wh/wl bf16 planes; zero esum.
// ---------------------------------------------------------------------------
__global__ __launch_bounds__(256) void wsplit(
    const float* __restrict__ wg, short* __restrict__ wh,
    short* __restrict__ wl, float* __restrict__ esum) {
  const int i = blockIdx.x * 256 + threadIdx.x;       // float4 granule
  const float4 v = ((const float4*)wg)[i];
  const float a[4] = {v.x, v.y, v.z, v.w};
  short4 h, l;
  short* hp = &h.x; short* lp = &l.x;
#pragma unroll
  for (int j = 0; j < 4; ++j) {
    const __hip_bfloat16 hb = __float2bfloat16(a[j]);
    const float r = a[j] - __bfloat162float(hb);
    hp[j] = __builtin_bit_cast(short, hb);
    lp[j] = __builtin_bit_cast(short, __float2bfloat16(r));
  }
  ((short4*)wh)[i] = h;
  ((short4*)wl)[i] = l;
  if (blockIdx.x == 0 && threadIdx.x < NEXP) esum[threadIdx.x] = 0.f;
}

// ---------------------------------------------------------------------------
// Restructured GEMM + fused softmax. 512 blocks x 256 thr (4 waves, 2 blk/CU).
// Block = 16 tokens x 64 experts x K=4096. Wave = kc (K-quarter, 1024);
// each wave loops et over all 4 expert tiles, reusing ONE A-frag split per
// step (4x fewer A-reads & split8 than R11). 32 steps of BK=32.
//
// LDS per buffer (40KB): A [0,8K): row(tok)=512B, 32 slots of 16B; the 32B
// A-pair is stored half0 at slot (q&8)|((q&7)^(r&7)), half1 at +16 slots ->
// conflict-free reads (8 lanes/bank-group). B [8K,40K): plane(2) x 16KB;
// row(expert)=256B, 16 slots; slot = (q&8)|((q&7)^(e&7)). Staging uses
// linear LDS dest + inverse-swizzled global source (G21). Double-buffered,
// counted vwait<10> (own stage retired, next stage in flight), 2 barriers.
// Epilogue: kc-quad reduce in LDS + softmax/argmax (4 waves x 4 tokens).
// ---------------------------------------------------------------------------
__global__ __launch_bounds__(256, 2) void gemm_softmax(
    const float* __restrict__ x, const short* __restrict__ wh,
    const short* __restrict__ wl, int* __restrict__ idx,
    float* __restrict__ gval, float* __restrict__ esum) {
  __shared__ __align__(16) char LDS[81920];           // 2 x 40KB
  const int tid  = threadIdx.x;
  const int t0   = blockIdx.x * 16;
  const int wid  = tid >> 6;           // = kc (K-quarter)
  const int lane = tid & 63;
  const int kc   = wid;
  const int mrow = lane & 15;          // token row / expert col within tile
  const int kg   = lane >> 4;          // k-subgroup
  const int q    = kc * 4 + kg;        // logical 8-elem pair id (0..15)

  // ---- staging sources (inverse-swizzled; content advances by +32 elems/step)
  const float* asrc[2];
#pragma unroll
  for (int c = 0; c < 2; ++c) {
    const int ga = c * 256 + tid;      // A granule id (0..511)
    const int r  = ga >> 5, s = ga & 31, hf = s >> 4, t = s & 15;
    const int ql = (t & 8) | ((t & 7) ^ (r & 7));
    asrc[c] = x + (size_t)(t0 + r) * MDIM + (ql >> 2) * 1024 + (ql & 3) * 8 + hf * 4;
  }
  const short* bsrc[8];
#pragma unroll
  for (int c = 0; c < 8; ++c) {
    const int gb = c * 256 + tid;      // B granule id (0..2047)
    const int p  = gb >> 10, rem = gb & 1023, e = rem >> 4, s2 = rem & 15;
    const int ql = (s2 & 8) | ((s2 & 7) ^ (e & 7));
    bsrc[c] = (p ? wl : wh) + (size_t)e * MDIM + (ql >> 2) * 1024 + (ql & 3) * 8;
  }

  // ---- frag read addresses (expi&7 == mrow&7, so one slot serves A and B)
  const int aslot = (q & 8) | ((q & 7) ^ (mrow & 7));
  const int abyte = mrow * 512 + aslot * 16;

  f32x4 acc[4] = {{0.f,0.f,0.f,0.f},{0.f,0.f,0.f,0.f},
                  {0.f,0.f,0.f,0.f},{0.f,0.f,0.f,0.f}};

  auto stage = [&](int j) {
    const int b = (j & 1) * 40960;
#pragma unroll
    for (int c = 0; c < 2; ++c)
      gll16(asrc[c] + j * 32, LDS + b + (c * 256 + tid) * 16);
#pragma unroll
    for (int c = 0; c < 8; ++c)
      gll16(bsrc[c] + j * 32, LDS + b + 8192 + (c * 256 + tid) * 16);
  };
  auto compute = [&](int k) {
    const int b = (k & 1) * 40960;
    const f32x4 a0 = *(const f32x4*)(LDS + b + abyte);
    const f32x4 a1 = *(const f32x4*)(LDS + b + abyte + 256);  // half1 = +16 slots
    const float fa[8] = {a0[0], a0[1], a0[2], a0[3], a1[0], a1[1], a1[2], a1[3]};
    bf16x8 ah, al;
    split8(fa, ah, al);
#pragma unroll
    for (int et = 0; et < 4; ++et) {
      const int bb = b + 8192 + (et * 16 + mrow) * 256 + aslot * 16;
      const bf16x8 bh = *(const bf16x8*)(LDS + bb);
      const bf16x8 bl = *(const bf16x8*)(LDS + bb + 16384);
      acc[et] = __builtin_amdgcn_mfma_f32_16x16x32_bf16(ah, bh, acc[et], 0, 0, 0);
      acc[et] = __builtin_amdgcn_mfma_f32_16x16x32_bf16(ah, bl, acc[et], 0, 0, 0);
      acc[et] = __builtin_amdgcn_mfma_f32_16x16x32_bf16(al, bh, acc[et], 0, 0, 0);
    }
  };

  stage(0);
#pragma unroll 2
  for (int k = 0; k < 31; ++k) {
    stage(k + 1);                      // 10 loads into buf (k+1)&1
    vwait<10>();                       // my stage(k) retired; stage(k+1) in flight
    barrier_now();                     // all waves: buf k&1 fully written
    compute(k);                        // ds_reads all consumed by MFMAs
    barrier_now();                     // all reads of buf k&1 done
  }
  vwait<0>();
  barrier_now();
  compute(31);
  __syncthreads();                     // drain; reuse LDS for epilogue

  // ---- epilogue: kc-quad reduction through LDS ----
  // C/D layout: col = lane&15 (expert), row = kg*4 + r (token)
  float* redF = (float*)LDS;           // [kc(4)][tok(16)][exp(64)] = 16KB
#pragma unroll
  for (int et = 0; et < 4; ++et)
#pragma unroll
    for (int r = 0; r < 4; ++r)
      redF[(kc * 16 + kg * 4 + r) * 64 + et * 16 + mrow] = acc[et][r];
  __syncthreads();

  // ---- softmax + argmax (tie -> min index): 4 waves x 4 tokens ----
  float gl = 0.f;
#pragma unroll
  for (int j = 0; j < 4; ++j) {
    const int tk = wid * 4 + j;
    float v = 0.f;
#pragma unroll
    for (int c = 0; c < 4; ++c) v += redF[(c * 16 + tk) * 64 + lane];
    float m = v; int mi = lane;
#pragma unroll
    for (int d = 32; d >= 1; d >>= 1) {
      const float om = __shfl_xor(m, d);
      const int   oi = __shfl_xor(mi, d);
      if (om > m || (om == m && oi < mi)) { m = om; mi = oi; }
    }
    const float e = expf(v - m);
    float denom = e;
#pragma unroll
    for (int d = 32; d >= 1; d >>= 1) denom += __shfl_xor(denom, d);
    gl += e / denom;
    if (lane == 0) { idx[t0 + tk] = mi; gval[t0 + tk] = 1.0f / denom; }
  }

  float* sgF = (float*)(LDS + 16384);  // [4][64], disjoint from red
  sgF[wid * 64 + lane] = gl;
  __syncthreads();
  if (tid < 64)
    atomicAdd(&esum[tid], sgF[tid] + sgF[64 + tid] + sgF[128 + tid] + sgF[192 + tid]);
}

// ---------------------------------------------------------------------------
// Per-expert scan + scatter + l_aux. One wave per expert, idx staged in LDS.
// ---------------------------------------------------------------------------
__global__ __launch_bounds__(256) void scan_scatter(
    const int* __restrict__ idx, const float* __restrict__ gval,
    const float* __restrict__ esum, float* __restrict__ out) {
  __shared__ int sidx[T_TOK];           // 32 KB
  const int tid = threadIdx.x;
  for (int i = tid; i < T_TOK / 4; i += 256)
    ((int4*)sidx)[i] = ((const int4*)idx)[i];
  __syncthreads();

  const int e    = blockIdx.x * 4 + (tid >> 6);
  const int lane = tid & 63;
  int carry = 0;
#pragma unroll 4
  for (int base = 0; base < T_TOK; base += 64) {
    const int t = base + lane;
    const bool flag = (sidx[t] == e);
    const unsigned long long mask = __ballot(flag);
    if (flag) {
      const int p = carry + __popcll(mask & ((1ull << lane) - 1ull));
      if (p < CAP) {
        const size_t off = ((size_t)t * NEXP + e) * CAP + p;
        out[1 + off]       = gval[t];
        out[1 + TEC + off] = 1.0f;
      }
    }
    carry += __popcll(mask);
  }
  if (lane == 0)                        // ce uses pre-drop count = carry
    atomicAdd(out, esum[e] * (float)carry *
                   ((float)NEXP / ((float)T_TOK * (float)T_TOK)));
}

extern "C" void kernel_launch(void* const* d_in, const int* in_sizes, int n_in,
                              void* d_out, int out_size, void* d_ws, size_t ws_size,
                              hipStream_t stream) {
  const float* x  = (const float*)d_in[0];
  const float* wg = (const float*)d_in[1];
  float* out = (float*)d_out;

  short* wh   = (short*)d_ws;                               // 64*4096 bf16
  short* wl   = wh + (size_t)NEXP * MDIM;
  int*   idx  = (int*)(wl + (size_t)NEXP * MDIM);
  float* gval = (float*)(idx + T_TOK);
  float* esum = (float*)(gval + T_TOK);

  wsplit<<<(NEXP * MDIM / 4) / 256, 256, 0, stream>>>(wg, wh, wl, esum);
  gemm_softmax<<<T_TOK / 16, 256, 0, stream>>>(x, wh, wl, idx, gval, esum);
  hipMemsetAsync(out, 0, OUTN * sizeof(float), stream);
  scan_scatter<<<NEXP / 4, 256, 0, stream>>>(idx, gval, esum, out);
}